// Round 2
// baseline (20450.015 us; speedup 1.0000x reference)
//
#include <hip/hip_runtime.h>
#include <hip/hip_bf16.h>
#include <cstdint>
#include <cstddef>

typedef unsigned short u16;
typedef __attribute__((ext_vector_type(8))) short short8;   // 8 bf16 (4 VGPRs)
typedef __attribute__((ext_vector_type(4))) float f32x4;    // 4 fp32 acc

#define L_SEQ 512
#define NB    64
#define HID_  1024
#define EMB_  512
#define DIN   1536          // HID + EMB
#define NKS   48            // DIN / 32 (K-steps of the 16x16x32 MFMA)
#define ARS   1544          // A-tile row stride in u16 (1536 + 8 pad -> b128 granule stride odd)

__device__ __forceinline__ u16 f2b(float f) {
    uint32_t u = __float_as_uint(f);
    u = (u + 0x7FFFu + ((u >> 16) & 1u)) >> 16;   // RNE fp32 -> bf16
    return (u16)u;
}

// ---------- P1: emb fp32 -> bf16 (32000x512) ----------
__global__ void cvt_emb_k(const float* __restrict__ src, u16* __restrict__ dst) {
    size_t i = ((size_t)blockIdx.x * blockDim.x + threadIdx.x) * 8;
    float4 a = *(const float4*)(src + i);
    float4 b = *(const float4*)(src + i + 4);
    short8 v;
    v[0] = (short)f2b(a.x); v[1] = (short)f2b(a.y);
    v[2] = (short)f2b(a.z); v[3] = (short)f2b(a.w);
    v[4] = (short)f2b(b.x); v[5] = (short)f2b(b.y);
    v[6] = (short)f2b(b.z); v[7] = (short)f2b(b.w);
    *(short8*)(dst + i) = v;
}

// ---------- P2: pack 4 gate weights into B-fragment order ----------
// whxp[(ug*4+gate)*48 + ks][lane][8 elems], elem e at k = ks*32 + (lane>>4)*8 + e,
// col = ug*16 + (lane&15). Same (lane,e)->k convention as the A fragments, so any
// hardware k-permutation cancels.
__global__ void pack_w_k(const float* __restrict__ Wi, const float* __restrict__ Wf,
                         const float* __restrict__ Wc, const float* __restrict__ Wo,
                         u16* __restrict__ whxp) {
    int b  = blockIdx.x;              // b = (ug*4+gw)*48 + ks
    int ks = b % NKS;
    int gw = (b / NKS) & 3;
    int ug = b / (NKS * 4);
    const float* W = (gw == 0) ? Wi : (gw == 1) ? Wf : (gw == 2) ? Wc : Wo;
    int t  = threadIdx.x;
    int l  = t & 63;
    int ep = t >> 6;                  // element-pair 0..3
    int k   = ks * 32 + ((l >> 4) * 8) + ep * 2;
    int col = ug * 16 + (l & 15);
    float v0 = W[(size_t)k * HID_ + col];
    float v1 = W[(size_t)(k + 1) * HID_ + col];
    uint32_t pk = (uint32_t)f2b(v0) | ((uint32_t)f2b(v1) << 16);
    size_t dst = (((size_t)b) * 64 + l) * 8 + (size_t)ep * 2;
    *(uint32_t*)(whxp + dst) = pk;
}

// ---------- P3: zero the barrier counters (ws is poisoned 0xAA every call) ----------
__global__ void zero_cnt_k(uint32_t* __restrict__ cnt) {
    cnt[blockIdx.x * 256 + threadIdx.x] = 0u;
}

// ---------- Persistent LSTM kernel: one launch, 512 steps ----------
// grid: 256 WGs, bid = bj*64 + ug. block: 256 threads = 4 waves; wave w = gate w.
// All 256 WGs are co-resident (grid <= #CUs), so a spin barrier among the 64 WGs
// sharing a batch-group (bj) is deadlock-free. Weights (48 B-fragments = 192 VGPRs),
// bias, and the c-state (1 float/thread) live in registers for all 512 steps.
__global__ __launch_bounds__(256, 1) void lstm_persist_k(
    const u16* __restrict__ whxp, const u16* __restrict__ embB,
    const int* __restrict__ x,
    const float* __restrict__ bi, const float* __restrict__ bf_,
    const float* __restrict__ bc, const float* __restrict__ bo,
    u16* __restrict__ hb, uint32_t* __restrict__ cnt,
    float* __restrict__ out)
{
    __shared__ __align__(16) u16 Atile[16][ARS];   // [batch row][k] (0..1023 h, 1024..1535 xe)
    __shared__ float gbuf[4][16][17];              // [gate][row][unit]

    const int tid = threadIdx.x;
    const int w   = tid >> 6;         // gate index for this wave
    const int l   = tid & 63;
    const int ug  = blockIdx.x & 63;
    const int bj  = blockIdx.x >> 6;
    const int brow0 = bj * 16;

    // ---- B fragments: held in VGPRs for the whole sequence ----
    short8 bw[NKS];
    {
        const short8* bp = (const short8*)whxp + ((size_t)(ug * 4 + w) * NKS) * 64 + l;
        #pragma unroll
        for (int ks = 0; ks < NKS; ++ks) bw[ks] = bp[ks * 64];
    }
    const float* bptr = (w == 0) ? bi : (w == 1) ? bf_ : (w == 2) ? bc : bo;
    const float bias = bptr[ug * 16 + (l & 15)];

    // elementwise identity of this thread (fixed for the whole sequence)
    const int erow = tid >> 4;        // batch row in tile 0..15
    const int eu   = tid & 15;        // unit in group   0..15
    const size_t cidx = (size_t)(brow0 + erow) * HID_ + (size_t)ug * 16 + eu;
    float creg = 0.f;                 // persistent c-state, never touches memory

    // ---- Prologue: zero h-part of A-tile, stage xe_0 ----
    {
        uint4 z = make_uint4(0u, 0u, 0u, 0u);
        #pragma unroll
        for (int it = 0; it < 8; ++it) {
            int i = tid * 4 + it * 1024;
            *(uint4*)(&Atile[i >> 9][(i & 511) * 2]) = z;
        }
        #pragma unroll
        for (int it = 0; it < 4; ++it) {
            int i   = tid * 4 + it * 1024;
            int row = i >> 8;
            int k32 = i & 255;
            int token = x[0 * NB + brow0 + row];
            uint4 v = *(const uint4*)((const uint32_t*)embB + (size_t)token * 256 + k32);
            *(uint4*)(&Atile[row][1024 + k32 * 2]) = v;
        }
    }
    __syncthreads();

    for (int t = 0; t < L_SEQ; ++t) {
        // ---- gates: bias + A(16x1536) @ W(1536x16) ----
        f32x4 acc0 = {bias, bias, bias, bias};
        f32x4 acc1 = {0.f, 0.f, 0.f, 0.f};
        const u16* arow = &Atile[l & 15][(l >> 4) * 8];
        #pragma unroll
        for (int ks = 0; ks < NKS; ks += 2) {
            short8 a0 = *(const short8*)(arow + ks * 32);
            short8 a1 = *(const short8*)(arow + ks * 32 + 32);
            acc0 = __builtin_amdgcn_mfma_f32_16x16x32_bf16(a0, bw[ks],     acc0, 0, 0, 0);
            acc1 = __builtin_amdgcn_mfma_f32_16x16x32_bf16(a1, bw[ks + 1], acc1, 0, 0, 0);
        }
        {
            int col = l & 15, rg = l >> 4;
            #pragma unroll
            for (int r = 0; r < 4; ++r)
                gbuf[w][rg * 4 + r][col] = acc0[r] + acc1[r];
        }
        __syncthreads();   // s1: gbuf complete

        // ---- elementwise update (c in register) ----
        {
            float gi = gbuf[0][erow][eu];
            float gf = gbuf[1][erow][eu];
            float gc = gbuf[2][erow][eu];
            float go = gbuf[3][erow][eu];
            float fi = 1.f / (1.f + __expf(-gi));
            float ff = 1.f / (1.f + __expf(-gf));
            float fo = 1.f / (1.f + __expf(-go));
            float tc = 1.f - 2.f / (__expf(2.f * gc) + 1.f);     // tanh(gc)
            float cn = ff * creg + fi * tc;
            float th = 1.f - 2.f / (__expf(2.f * cn) + 1.f);     // tanh(cn)
            float hn = fo * th;
            creg = cn;
            out[(size_t)t * (NB * HID_) + cidx] = hn;
            (hb + (size_t)(t & 1) * (NB * HID_))[cidx] = f2b(hn);
        }

        if (t + 1 < L_SEQ) {
            // ---- cluster barrier: release own h block, arrive ----
            __threadfence();                 // release: writeback (wbl2)
            __syncthreads();                 // s2: all waves' stores+fences done
            if (tid == 0)
                __hip_atomic_fetch_add(&cnt[bj * L_SEQ + t], 1u,
                                       __ATOMIC_RELAXED, __HIP_MEMORY_SCOPE_AGENT);

            // ---- overlap: stage xe_{t+1} while waiting ----
            #pragma unroll
            for (int it = 0; it < 4; ++it) {
                int i   = tid * 4 + it * 1024;
                int row = i >> 8;
                int k32 = i & 255;
                int token = x[(t + 1) * NB + brow0 + row];
                uint4 v = *(const uint4*)((const uint32_t*)embB + (size_t)token * 256 + k32);
                *(uint4*)(&Atile[row][1024 + k32 * 2]) = v;
            }

            if (tid == 0) {
                while (__hip_atomic_load(&cnt[bj * L_SEQ + t],
                                         __ATOMIC_RELAXED, __HIP_MEMORY_SCOPE_AGENT) < 64u)
                    __builtin_amdgcn_s_sleep(1);
            }
            __syncthreads();                 // s3: barrier passed for whole WG
            __threadfence();                 // acquire: invalidate stale L1/L2

            // ---- stage h_t (16 rows x 1024 units, bf16) into A-tile ----
            {
                const uint32_t* hsrc = (const uint32_t*)(hb + (size_t)(t & 1) * (NB * HID_));
                #pragma unroll
                for (int it = 0; it < 8; ++it) {
                    int i   = tid * 4 + it * 1024;
                    int row = i >> 9;
                    int k32 = i & 511;
                    uint4 v = *(const uint4*)(hsrc + (size_t)(brow0 + row) * 512 + k32);
                    *(uint4*)(&Atile[row][k32 * 2]) = v;
                }
            }
            __syncthreads();                 // s4: A-tile ready for step t+1
        }
    }
}

extern "C" void kernel_launch(void* const* d_in, const int* in_sizes, int n_in,
                              void* d_out, int out_size, void* d_ws, size_t ws_size,
                              hipStream_t stream) {
    const int*   x   = (const int*)d_in[0];
    const float* emb = (const float*)d_in[1];
    const float* Wi  = (const float*)d_in[2];
    const float* bi  = (const float*)d_in[3];
    const float* Wf  = (const float*)d_in[4];
    const float* bf  = (const float*)d_in[5];
    const float* Wc  = (const float*)d_in[6];
    const float* bc  = (const float*)d_in[7];
    const float* Wo  = (const float*)d_in[8];
    const float* bo  = (const float*)d_in[9];
    float* out = (float*)d_out;

    // Workspace carve (~45.6 MB):
    char* ws = (char*)d_ws;
    u16*      whxp = (u16*)ws;                                    // 12,582,912 B packed weights
    u16*      embB = (u16*)(ws + 12582912);                       // 32,768,000 B emb bf16
    u16*      hb   = (u16*)(ws + 12582912 + 32768000);            //    262,144 B h ping-pong
    uint32_t* cnt  = (uint32_t*)(ws + 12582912 + 32768000 + 262144); //   8,192 B barrier counters

    cvt_emb_k<<<8000, 256, 0, stream>>>(emb, embB);
    pack_w_k<<<64 * 4 * NKS, 256, 0, stream>>>(Wi, Wf, Wc, Wo, whxp);
    zero_cnt_k<<<8, 256, 0, stream>>>(cnt);

    lstm_persist_k<<<256, 256, 0, stream>>>(whxp, embB, x, bi, bf, bc, bo,
                                            hb, cnt, out);
}

// Round 3
// 2854.074 us; speedup vs baseline: 7.1652x; 7.1652x over previous
//
#include <hip/hip_runtime.h>
#include <hip/hip_bf16.h>
#include <cstdint>
#include <cstddef>

typedef unsigned short u16;
typedef __attribute__((ext_vector_type(8))) short short8;   // 8 bf16 (4 VGPRs)
typedef __attribute__((ext_vector_type(4))) float f32x4;    // 4 fp32 acc

#define L_SEQ 512
#define NB    64
#define HID_  1024
#define EMB_  512
#define DIN   1536          // HID + EMB
#define NKS   48            // DIN / 32 (K-steps of the 16x16x32 MFMA)
#define NKS_H 32            // K-steps covering h (k 0..1023)
#define ARS   1544          // A-tile row stride in u16 (odd 16B-granule stride)
#define HSEQ  (NB * HID_)   // u16 elements per h snapshot (65536)

__device__ __forceinline__ u16 f2b(float f) {
    uint32_t u = __float_as_uint(f);
    u = (u + 0x7FFFu + ((u >> 16) & 1u)) >> 16;   // RNE fp32 -> bf16
    return (u16)u;
}

// ---------- P1: pack 4 gate weights into B-fragment order ----------
// whxp[(ug*4+gate)*48 + ks][lane][8 elems], elem e at k = ks*32 + (lane>>4)*8 + e,
// col = ug*16 + (lane&15). Same (lane,e)->k convention as the A fragments, so any
// hardware k-permutation cancels.
__global__ void pack_w_k(const float* __restrict__ Wi, const float* __restrict__ Wf,
                         const float* __restrict__ Wc, const float* __restrict__ Wo,
                         u16* __restrict__ whxp) {
    int b  = blockIdx.x;              // b = (ug*4+gw)*48 + ks
    int ks = b % NKS;
    int gw = (b / NKS) & 3;
    int ug = b / (NKS * 4);
    const float* W = (gw == 0) ? Wi : (gw == 1) ? Wf : (gw == 2) ? Wc : Wo;
    int t  = threadIdx.x;
    int l  = t & 63;
    int ep = t >> 6;                  // element-pair 0..3
    int k   = ks * 32 + ((l >> 4) * 8) + ep * 2;
    int col = ug * 16 + (l & 15);
    float v0 = W[(size_t)k * HID_ + col];
    float v1 = W[(size_t)(k + 1) * HID_ + col];
    uint32_t pk = (uint32_t)f2b(v0) | ((uint32_t)f2b(v1) << 16);
    size_t dst = (((size_t)b) * 64 + l) * 8 + (size_t)ep * 2;
    *(uint32_t*)(whxp + dst) = pk;
}

// ---------- P2: zero the flag array (ws is poisoned 0xAA every timed call) ----------
__global__ void zero_flags_k(uint32_t* __restrict__ flags) {
    flags[threadIdx.x] = 0u;
}

// ---------- Persistent LSTM kernel: one launch, 512 steps ----------
// grid: 256 WGs, bid = bj*64 + ug. block: 256 threads = 4 waves; wave w = gate w.
// All 256 WGs co-resident (grid <= #CUs; verified by round-2 run). Sync within a
// 64-WG batch-group cluster via per-WG flag words (no atomic RMW, no threadfence):
//   producer: h stores = agent-scope relaxed atomic stores (write-through to L3)
//             -> vmcnt(0) drain (implicit in __syncthreads, + explicit asm)
//             -> flags[bj][ug] = t+1 (agent-scope relaxed store)
//   consumer: 64 lanes of wave 0 poll the 64 flags, __all(flag > t) -> pass.
// h ring is L_SEQ-deep so every consumer load is a fresh address: guaranteed
// L1/L2 miss, served from L3 where producers wrote through. No stale-line hazard.
__global__ __launch_bounds__(256, 1) void lstm_persist_k(
    const u16* __restrict__ whxp, const float* __restrict__ emb,
    const int* __restrict__ x,
    const float* __restrict__ bi, const float* __restrict__ bf_,
    const float* __restrict__ bc, const float* __restrict__ bo,
    u16* __restrict__ hseq, uint32_t* __restrict__ flags,
    float* __restrict__ out)
{
    __shared__ __align__(16) u16 Atile[16][ARS];   // [batch row][k] (0..1023 h, 1024..1535 xe)
    __shared__ float gbuf[4][16][17];              // [gate][row][unit]

    const int tid = threadIdx.x;
    const int w   = tid >> 6;         // gate index for this wave
    const int l   = tid & 63;
    const int ug  = blockIdx.x & 63;
    const int bj  = blockIdx.x >> 6;
    const int brow0 = bj * 16;

    // ---- B fragments: held in registers for the whole sequence ----
    short8 bw[NKS];
    {
        const short8* bp = (const short8*)whxp + ((size_t)(ug * 4 + w) * NKS) * 64 + l;
        #pragma unroll
        for (int ks = 0; ks < NKS; ++ks) bw[ks] = bp[ks * 64];
    }
    const float* bptr = (w == 0) ? bi : (w == 1) ? bf_ : (w == 2) ? bc : bo;
    const float bias = bptr[ug * 16 + (l & 15)];

    // elementwise identity of this thread (fixed for the whole sequence)
    const int erow = tid >> 4;        // batch row in tile 0..15
    const int eu   = tid & 15;        // unit in group   0..15
    const size_t cidx = (size_t)(brow0 + erow) * HID_ + (size_t)ug * 16 + eu;
    float creg = 0.f;                 // persistent c-state, never touches memory

    // xe gather identity
    const int grow = tid >> 4;        // batch row this thread gathers
    const int gc0  = (tid & 15) * 32; // first emb column (32 floats per thread)

    // ---- Prologue: gather + stage xe_0 ----
    {
        int token = x[brow0 + grow];
        const float* es = emb + (size_t)token * EMB_ + gc0;
        #pragma unroll
        for (int j = 0; j < 4; ++j) {
            float4 a = *(const float4*)(es + j * 8);
            float4 b = *(const float4*)(es + j * 8 + 4);
            short8 v;
            v[0] = (short)f2b(a.x); v[1] = (short)f2b(a.y);
            v[2] = (short)f2b(a.z); v[3] = (short)f2b(a.w);
            v[4] = (short)f2b(b.x); v[5] = (short)f2b(b.y);
            v[6] = (short)f2b(b.z); v[7] = (short)f2b(b.w);
            *(short8*)(&Atile[grow][1024 + gc0 + j * 8]) = v;
        }
    }
    __syncthreads();

    for (int t = 0; t < L_SEQ; ++t) {
        // ---- gates: bias + A(16x1536) @ W(1536x16), 4 accumulator chains ----
        f32x4 acc0 = {bias, bias, bias, bias};
        f32x4 acc1 = {0.f, 0.f, 0.f, 0.f};
        f32x4 acc2 = {0.f, 0.f, 0.f, 0.f};
        f32x4 acc3 = {0.f, 0.f, 0.f, 0.f};
        const u16* arow = &Atile[l & 15][(l >> 4) * 8];

        // xe part (ks 32..47) — always valid on loop entry
        #pragma unroll
        for (int ks = NKS_H; ks < NKS; ks += 4) {
            acc0 = __builtin_amdgcn_mfma_f32_16x16x32_bf16(*(const short8*)(arow + ks * 32),        bw[ks],     acc0, 0, 0, 0);
            acc1 = __builtin_amdgcn_mfma_f32_16x16x32_bf16(*(const short8*)(arow + (ks + 1) * 32),  bw[ks + 1], acc1, 0, 0, 0);
            acc2 = __builtin_amdgcn_mfma_f32_16x16x32_bf16(*(const short8*)(arow + (ks + 2) * 32),  bw[ks + 2], acc2, 0, 0, 0);
            acc3 = __builtin_amdgcn_mfma_f32_16x16x32_bf16(*(const short8*)(arow + (ks + 3) * 32),  bw[ks + 3], acc3, 0, 0, 0);
        }
        // h part (ks 0..31) — h_0 = 0, so skip at t=0
        if (t > 0) {
            #pragma unroll
            for (int ks = 0; ks < NKS_H; ks += 4) {
                acc0 = __builtin_amdgcn_mfma_f32_16x16x32_bf16(*(const short8*)(arow + ks * 32),        bw[ks],     acc0, 0, 0, 0);
                acc1 = __builtin_amdgcn_mfma_f32_16x16x32_bf16(*(const short8*)(arow + (ks + 1) * 32),  bw[ks + 1], acc1, 0, 0, 0);
                acc2 = __builtin_amdgcn_mfma_f32_16x16x32_bf16(*(const short8*)(arow + (ks + 2) * 32),  bw[ks + 2], acc2, 0, 0, 0);
                acc3 = __builtin_amdgcn_mfma_f32_16x16x32_bf16(*(const short8*)(arow + (ks + 3) * 32),  bw[ks + 3], acc3, 0, 0, 0);
            }
        }
        {
            int col = l & 15, rg = l >> 4;
            #pragma unroll
            for (int r = 0; r < 4; ++r)
                gbuf[w][rg * 4 + r][col] = (acc0[r] + acc1[r]) + (acc2[r] + acc3[r]);
        }
        __syncthreads();   // s1: gbuf complete

        // ---- elementwise update (c in register); publish h_t ----
        {
            float gi = gbuf[0][erow][eu];
            float gf = gbuf[1][erow][eu];
            float gc = gbuf[2][erow][eu];
            float go = gbuf[3][erow][eu];
            float fi = 1.f / (1.f + __expf(-gi));
            float ff = 1.f / (1.f + __expf(-gf));
            float fo = 1.f / (1.f + __expf(-go));
            float tc = 1.f - 2.f / (__expf(2.f * gc) + 1.f);     // tanh(gc)
            float cn = ff * creg + fi * tc;
            float th = 1.f - 2.f / (__expf(2.f * cn) + 1.f);     // tanh(cn)
            float hn = fo * th;
            creg = cn;
            out[(size_t)t * (NB * HID_) + cidx] = hn;
            __hip_atomic_store(hseq + (size_t)t * HSEQ + cidx, f2b(hn),
                               __ATOMIC_RELAXED, __HIP_MEMORY_SCOPE_AGENT);
        }

        if (t + 1 < L_SEQ) {
            asm volatile("s_waitcnt vmcnt(0)" ::: "memory");  // h stores at coherence point
            __syncthreads();              // s2: all 4 waves drained
            if (tid == 0)
                __hip_atomic_store(&flags[bj * 64 + ug], (uint32_t)(t + 1),
                                   __ATOMIC_RELAXED, __HIP_MEMORY_SCOPE_AGENT);

            // ---- overlap: gather xe_{t+1} into registers while others publish ----
            short8 xv[4];
            {
                int token = x[(t + 1) * NB + brow0 + grow];
                const float* es = emb + (size_t)token * EMB_ + gc0;
                #pragma unroll
                for (int j = 0; j < 4; ++j) {
                    float4 a = *(const float4*)(es + j * 8);
                    float4 b = *(const float4*)(es + j * 8 + 4);
                    short8 v;
                    v[0] = (short)f2b(a.x); v[1] = (short)f2b(a.y);
                    v[2] = (short)f2b(a.z); v[3] = (short)f2b(a.w);
                    v[4] = (short)f2b(b.x); v[5] = (short)f2b(b.y);
                    v[6] = (short)f2b(b.z); v[7] = (short)f2b(b.w);
                    xv[j] = v;
                }
            }

            // ---- flag-broadcast barrier: wave 0 polls all 64 flags ----
            if (tid < 64) {
                for (;;) {
                    uint32_t f = __hip_atomic_load(&flags[bj * 64 + tid],
                                                   __ATOMIC_RELAXED, __HIP_MEMORY_SCOPE_AGENT);
                    if (__all(f > (uint32_t)t)) break;
                    __builtin_amdgcn_s_sleep(2);
                }
            }
            __syncthreads();              // s3: h_t globally visible for whole cluster

            // ---- gather h_t (fresh addresses -> guaranteed miss to L3) ----
            uint4 hv[8];
            {
                const uint32_t* hsrc = (const uint32_t*)(hseq + (size_t)t * HSEQ);
                #pragma unroll
                for (int it = 0; it < 8; ++it) {
                    int i = tid * 4 + it * 1024;
                    hv[it] = *(const uint4*)(hsrc + (size_t)(brow0 + (i >> 9)) * 512 + (i & 511));
                }
            }
            // xe ds_writes first: hides part of the h-load latency
            #pragma unroll
            for (int j = 0; j < 4; ++j)
                *(short8*)(&Atile[grow][1024 + gc0 + j * 8]) = xv[j];
            #pragma unroll
            for (int it = 0; it < 8; ++it) {
                int i = tid * 4 + it * 1024;
                *(uint4*)(&Atile[i >> 9][(i & 511) * 2]) = hv[it];
            }
            __syncthreads();              // s4: A-tile ready for step t+1
        }
    }
}

extern "C" void kernel_launch(void* const* d_in, const int* in_sizes, int n_in,
                              void* d_out, int out_size, void* d_ws, size_t ws_size,
                              hipStream_t stream) {
    const int*   x   = (const int*)d_in[0];
    const float* emb = (const float*)d_in[1];
    const float* Wi  = (const float*)d_in[2];
    const float* bi  = (const float*)d_in[3];
    const float* Wf  = (const float*)d_in[4];
    const float* bf  = (const float*)d_in[5];
    const float* Wc  = (const float*)d_in[6];
    const float* bc  = (const float*)d_in[7];
    const float* Wo  = (const float*)d_in[8];
    const float* bo  = (const float*)d_in[9];
    float* out = (float*)d_out;

    // Workspace carve (~79.7 MB):
    char* ws = (char*)d_ws;
    u16*      whxp  = (u16*)ws;                          // 12,582,912 B packed weights (bf16)
    uint32_t* flags = (uint32_t*)(ws + 12582912);        //      4,096 B flag words (256 used)
    u16*      hseq  = (u16*)(ws + 12582912 + 4096);      // 67,108,864 B h ring (512 x 64 x 1024 bf16)

    pack_w_k<<<64 * 4 * NKS, 256, 0, stream>>>(Wi, Wf, Wc, Wo, whxp);
    zero_flags_k<<<1, 256, 0, stream>>>(flags);

    lstm_persist_k<<<256, 256, 0, stream>>>(whxp, emb, x, bi, bf, bc, bo,
                                            hseq, flags, out);
}

// Round 6
// 2724.298 us; speedup vs baseline: 7.5065x; 1.0476x over previous
//
#include <hip/hip_runtime.h>
#include <hip/hip_bf16.h>
#include <cstdint>
#include <cstddef>

typedef unsigned short u16;
typedef __attribute__((ext_vector_type(8))) short short8;   // 8 bf16 (4 VGPRs)
typedef __attribute__((ext_vector_type(4))) float f32x4;    // 4 fp32 acc

#define L_SEQ 512
#define NB    64
#define HID_  1024
#define EMB_  512
#define NKS   48            // K-steps (DIN=1536 / 32)
#define KQ_N  12            // K-steps per wave (K-quarter)
#define HSEQ  (NB * HID_)   // u16 per h snapshot (65536)

__device__ __forceinline__ u16 f2b(float f) {
    uint32_t u = __float_as_uint(f);
    u = (u + 0x7FFFu + ((u >> 16) & 1u)) >> 16;   // RNE fp32 -> bf16
    return (u16)u;
}

// ---------- P1: pack 4 gate weights into B-fragment order (proven r1-r3) ----------
// frag index ((ug*4+g)*48 + ks)*64 + lane; elem e at k = ks*32 + (lane>>4)*8 + e,
// col = ug*16 + (lane&15). Same (lane,e)->k convention as the A fragments.
__global__ void pack_w_k(const float* __restrict__ Wi, const float* __restrict__ Wf,
                         const float* __restrict__ Wc, const float* __restrict__ Wo,
                         u16* __restrict__ whxp) {
    int b  = blockIdx.x;              // b = (ug*4+gw)*48 + ks
    int ks = b % NKS;
    int gw = (b / NKS) & 3;
    int ug = b / (NKS * 4);
    const float* W = (gw == 0) ? Wi : (gw == 1) ? Wf : (gw == 2) ? Wc : Wo;
    int t  = threadIdx.x;
    int l  = t & 63;
    int ep = t >> 6;                  // element-pair 0..3
    int k   = ks * 32 + ((l >> 4) * 8) + ep * 2;
    int col = ug * 16 + (l & 15);
    float v0 = W[(size_t)k * HID_ + col];
    float v1 = W[(size_t)(k + 1) * HID_ + col];
    uint32_t pk = (uint32_t)f2b(v0) | ((uint32_t)f2b(v1) << 16);
    size_t dst = (((size_t)b) * 64 + l) * 8 + (size_t)ep * 2;
    *(uint32_t*)(whxp + dst) = pk;
}

// ---------- P2: zero flags (ws poisoned 0xAA before every timed call) ----------
__global__ void zero_flags_k(uint32_t* __restrict__ flags) {
    flags[threadIdx.x] = 0u;
}

// ---------- Persistent LSTM: 256 WGs x 256 thr (4 waves), cluster = 64 WGs ----------
// bid = bj*64 + ug. Wave w = K-quarter kq; each wave computes partial gates for all
// 4 gates x 16 units over its 384-k slice (bw[4][12] = 192 VGPRs, register-resident
// via waves_per_eu(1,1)). Partials reduced via gbuf[kq][g][row][unit].
// Sync (r3-proven): bf16 ring publish (agent store) -> vmcnt(0)+barrier -> flag ->
// 64-lane poll -> fresh-address ring gather (plain loads).
// Atile: XOR-swizzled [16 rows][192 granules of 16B]: granule ^= (row&7).
__global__ __launch_bounds__(256)
__attribute__((amdgpu_waves_per_eu(1, 1)))
void lstm_persist_k(
    const u16* __restrict__ whxp, const float* __restrict__ emb,
    const int* __restrict__ x,
    const float* __restrict__ bi, const float* __restrict__ bf_,
    const float* __restrict__ bc, const float* __restrict__ bo,
    u16* __restrict__ hseq, uint32_t* __restrict__ flags,
    float* __restrict__ out)
{
    __shared__ __align__(16) u16 As[16 * 1536];    // 49,152 B swizzled A-tile
    __shared__ float gbuf[4][4][16][16];           // 16,384 B [kq][gate][row][unit]

    const int tid = threadIdx.x;
    const int kq  = tid >> 6;         // K-quarter of this wave
    const int l   = tid & 63;
    const int ug  = blockIdx.x & 63;
    const int bj  = blockIdx.x >> 6;
    const int brow0 = bj * 16;

    // ---- B fragments: 48 frags = 192 VGPRs, resident for the whole sequence ----
    short8 bw0[KQ_N], bw1[KQ_N], bw2[KQ_N], bw3[KQ_N];
    {
        const short8* bp = (const short8*)whxp + ((size_t)(ug * 4) * NKS) * 64 + l;
        #pragma unroll
        for (int j = 0; j < KQ_N; ++j) {
            bw0[j] = bp[(0 * NKS + kq * KQ_N + j) * 64];
            bw1[j] = bp[(1 * NKS + kq * KQ_N + j) * 64];
            bw2[j] = bp[(2 * NKS + kq * KQ_N + j) * 64];
            bw3[j] = bp[(3 * NKS + kq * KQ_N + j) * 64];
        }
    }

    // MFMA lane identity
    const int arow = l & 15;          // A row
    const int aq   = l >> 4;          // k-subgroup
    const int k7   = arow & 7;        // swizzle key

    // elementwise identity
    const int erow = tid >> 4;        // 0..15
    const int eu   = tid & 15;        // 0..15
    const size_t cidx = (size_t)(brow0 + erow) * HID_ + (size_t)ug * 16 + eu;
    const float bias_i = bi[ug * 16 + eu];
    const float bias_f = bf_[ug * 16 + eu];
    const float bias_c = bc[ug * 16 + eu];
    const float bias_o = bo[ug * 16 + eu];
    float creg = 0.f;

    // xe gather identity
    const int grow = tid >> 4;
    const int gx   = tid & 15;        // 32-float chunk -> granules 128+gx*4 .. +3

    // ---- Prologue: zero h region (granules 0..127; zeros are swizzle-invariant) ----
    {
        uint4 z = make_uint4(0u, 0u, 0u, 0u);
        #pragma unroll
        for (int it = 0; it < 8; ++it) {
            int gidx = tid + it * 256;            // 0..2047
            int r_ = gidx >> 7, gr = gidx & 127;
            *(uint4*)(&As[r_ * 1536 + (((gr ^ (r_ & 7))) << 3)]) = z;
        }
        // xe_0
        int token = x[brow0 + grow];
        const float* es = emb + (size_t)token * EMB_ + gx * 32;
        #pragma unroll
        for (int jj = 0; jj < 4; ++jj) {
            float4 a = *(const float4*)(es + jj * 8);
            float4 b = *(const float4*)(es + jj * 8 + 4);
            short8 v;
            v[0] = (short)f2b(a.x); v[1] = (short)f2b(a.y);
            v[2] = (short)f2b(a.z); v[3] = (short)f2b(a.w);
            v[4] = (short)f2b(b.x); v[5] = (short)f2b(b.y);
            v[6] = (short)f2b(b.z); v[7] = (short)f2b(b.w);
            int gr = 128 + gx * 4 + jj;
            *(short8*)(&As[grow * 1536 + ((gr ^ (grow & 7)) << 3)]) = v;
        }
    }
    __syncthreads();

    for (int t = 0; t < L_SEQ; ++t) {
        // ---- MFMA: partial gates over this wave's K-quarter ----
        f32x4 p0 = {0.f, 0.f, 0.f, 0.f};
        f32x4 p1 = {0.f, 0.f, 0.f, 0.f};
        f32x4 p2 = {0.f, 0.f, 0.f, 0.f};
        f32x4 p3 = {0.f, 0.f, 0.f, 0.f};
        #pragma unroll
        for (int j = 0; j < KQ_N; ++j) {
            int gr = (kq * KQ_N + j) * 4 + aq;
            short8 av = *(const short8*)(&As[arow * 1536 + ((gr ^ k7) << 3)]);
            p0 = __builtin_amdgcn_mfma_f32_16x16x32_bf16(av, bw0[j], p0, 0, 0, 0);
            p1 = __builtin_amdgcn_mfma_f32_16x16x32_bf16(av, bw1[j], p1, 0, 0, 0);
            p2 = __builtin_amdgcn_mfma_f32_16x16x32_bf16(av, bw2[j], p2, 0, 0, 0);
            p3 = __builtin_amdgcn_mfma_f32_16x16x32_bf16(av, bw3[j], p3, 0, 0, 0);
        }
        {
            int col = l & 15, rg = l >> 4;
            #pragma unroll
            for (int r = 0; r < 4; ++r) {
                gbuf[kq][0][rg * 4 + r][col] = p0[r];
                gbuf[kq][1][rg * 4 + r][col] = p1[r];
                gbuf[kq][2][rg * 4 + r][col] = p2[r];
                gbuf[kq][3][rg * 4 + r][col] = p3[r];
            }
        }
        __syncthreads();   // s1: all partials in gbuf

        // ---- elementwise: reduce 4 partials, LSTM update, publish h_t ----
        {
            float gi = ((gbuf[0][0][erow][eu] + gbuf[1][0][erow][eu]) +
                        (gbuf[2][0][erow][eu] + gbuf[3][0][erow][eu])) + bias_i;
            float gf = ((gbuf[0][1][erow][eu] + gbuf[1][1][erow][eu]) +
                        (gbuf[2][1][erow][eu] + gbuf[3][1][erow][eu])) + bias_f;
            float gc = ((gbuf[0][2][erow][eu] + gbuf[1][2][erow][eu]) +
                        (gbuf[2][2][erow][eu] + gbuf[3][2][erow][eu])) + bias_c;
            float go = ((gbuf[0][3][erow][eu] + gbuf[1][3][erow][eu]) +
                        (gbuf[2][3][erow][eu] + gbuf[3][3][erow][eu])) + bias_o;
            float fi = 1.f / (1.f + __expf(-gi));
            float ff = 1.f / (1.f + __expf(-gf));
            float fo = 1.f / (1.f + __expf(-go));
            float tc = 1.f - 2.f / (__expf(2.f * gc) + 1.f);     // tanh(gc)
            float cn = ff * creg + fi * tc;
            float th = 1.f - 2.f / (__expf(2.f * cn) + 1.f);     // tanh(cn)
            float hn = fo * th;
            creg = cn;
            out[(size_t)t * (NB * HID_) + cidx] = hn;            // plain store
            __hip_atomic_store(hseq + (size_t)t * HSEQ + cidx, f2b(hn),
                               __ATOMIC_RELAXED, __HIP_MEMORY_SCOPE_AGENT);
        }

        if (t + 1 < L_SEQ) {
            asm volatile("s_waitcnt vmcnt(0)" ::: "memory");  // h at coherence point
            __syncthreads();              // s2: all 4 waves drained; gbuf/Atile reads done
            if (tid == 0)
                __hip_atomic_store(&flags[bj * 64 + ug], (uint32_t)(t + 1),
                                   __ATOMIC_RELAXED, __HIP_MEMORY_SCOPE_AGENT);

            // ---- xe_{t+1}: gather + cvt + swizzled ds_write (overlaps peers' publish) ----
            {
                int token = x[(t + 1) * NB + brow0 + grow];
                const float* es = emb + (size_t)token * EMB_ + gx * 32;
                float4 ea[8];
                #pragma unroll
                for (int jj = 0; jj < 8; ++jj) ea[jj] = *(const float4*)(es + jj * 4);
                #pragma unroll
                for (int jj = 0; jj < 4; ++jj) {
                    float4 a = ea[jj * 2], b = ea[jj * 2 + 1];
                    short8 v;
                    v[0] = (short)f2b(a.x); v[1] = (short)f2b(a.y);
                    v[2] = (short)f2b(a.z); v[3] = (short)f2b(a.w);
                    v[4] = (short)f2b(b.x); v[5] = (short)f2b(b.y);
                    v[6] = (short)f2b(b.z); v[7] = (short)f2b(b.w);
                    int gr = 128 + gx * 4 + jj;
                    *(short8*)(&As[grow * 1536 + ((gr ^ (grow & 7)) << 3)]) = v;
                }
            }

            // ---- flag-broadcast barrier: wave 0 polls the 64 cluster flags ----
            if (tid < 64) {
                for (;;) {
                    uint32_t f = __hip_atomic_load(&flags[bj * 64 + l],
                                                   __ATOMIC_RELAXED, __HIP_MEMORY_SCOPE_AGENT);
                    if (__all(f > (uint32_t)t)) break;
                    __builtin_amdgcn_s_sleep(1);
                }
            }
            __syncthreads();              // s3: h_t globally visible

            // ---- ring gather (fresh addresses -> miss to L3), swizzled ds_write ----
            {
                const uint4* hsrc = (const uint4*)(hseq + (size_t)t * HSEQ +
                                                   (size_t)brow0 * HID_);
                uint4 hv[8];
                #pragma unroll
                for (int it = 0; it < 8; ++it) hv[it] = hsrc[it * 256 + tid];
                #pragma unroll
                for (int it = 0; it < 8; ++it) {
                    int f16 = (it * 256 + tid) * 8;       // flat u16 index in 16x1024
                    int r_  = f16 >> 10;
                    int gr  = (f16 & 1023) >> 3;          // granule 0..127
                    *(uint4*)(&As[r_ * 1536 + ((gr ^ (r_ & 7)) << 3)]) = hv[it];
                }
            }
            __syncthreads();              // s4: A-tile ready for step t+1
        }
    }
}

extern "C" void kernel_launch(void* const* d_in, const int* in_sizes, int n_in,
                              void* d_out, int out_size, void* d_ws, size_t ws_size,
                              hipStream_t stream) {
    const int*   x   = (const int*)d_in[0];
    const float* emb = (const float*)d_in[1];
    const float* Wi  = (const float*)d_in[2];
    const float* bi  = (const float*)d_in[3];
    const float* Wf  = (const float*)d_in[4];
    const float* bf  = (const float*)d_in[5];
    const float* Wc  = (const float*)d_in[6];
    const float* bc  = (const float*)d_in[7];
    const float* Wo  = (const float*)d_in[8];
    const float* bo  = (const float*)d_in[9];
    float* out = (float*)d_out;

    // Workspace carve (~79.7 MB, r3-proven size):
    char* ws = (char*)d_ws;
    u16*      whxp  = (u16*)ws;                          // 12,582,912 B packed weights (bf16)
    uint32_t* flags = (uint32_t*)(ws + 12582912);        //      4,096 B flags (256 used)
    u16*      hseq  = (u16*)(ws + 12582912 + 4096);      // 67,108,864 B h ring (bf16)

    pack_w_k<<<64 * 4 * NKS, 256, 0, stream>>>(Wi, Wf, Wc, Wo, whxp);
    zero_flags_k<<<1, 256, 0, stream>>>(flags);

    lstm_persist_k<<<256, 256, 0, stream>>>(whxp, emb, x, bi, bf, bc, bo,
                                            hseq, flags, out);
}